// Round 7
// baseline (2039.564 us; speedup 1.0000x reference)
//
#include <hip/hip_runtime.h>

// RoutingCapsules on MI355X (gfx950)
// x: [B=32, Nin=2048, Din=16] f32
// W: [1, Nin=2048, Nout=64, Dout=32, Din=16] f32
// out v: [B=32, Nout=64, Dout=32] f32
//
// 3 fused W-sweeps (u_hat recomputed, never materialized):
//   pass1: c uniform     -> s1 = (1/64) sum_n u_hat        -> v1
//   pass2: logits=u.v1   -> s2                             -> v2
//   pass3: logits=u.(v1+v2)  (b3 = a1+a2)                  -> v3 = out
//
// Round-7: round 6 showed pass2/3 at 277 us vs pass1 ~75 us -- the 64-wide
// softmax was recomputed redundantly by every thread (88 LDS-pipe ops + 8 exp
// + 8 div per thread per nn). Fix: block-level softmax dedup. Phase A computes
// u in registers (q-loop keeps W frag at 8 regs so u0r/u1r persist across the
// barrier -- no ustash LDS). Phase B: waves 0-7 compute c[bb][o] once. Phase C:
// everyone reads c and accumulates. 2 barriers/nn, single-buffered LDS (12.5KB).

#define B_   32
#define NIN  2048
#define DIN  16
#define NOUT 64
#define DOUT 32
#define BQ   8                          // batches per block
#define NCHB 16                         // n per block
#define CG   (NIN / NCHB)               // 128 chunk-groups
#define NBLK (CG * (B_ / BQ))           // 512 blocks
#define TPB  1024
#define PART_PER_BLK (BQ * NOUT * DOUT / 2)   // 8192 float2 per block (64 KB)

template<int PASS, bool ATOMIC>
__global__ __launch_bounds__(TPB)
void caps_pass(const float* __restrict__ W, const float* __restrict__ x,
               const float* __restrict__ v_in, float* __restrict__ s_out,
               float2* __restrict__ part)
{
    const int t    = threadIdx.x;     // 0..1023
    const int o    = t >> 4;          // 0..63   capsule-out index
    const int dg   = t & 15;          // 0..15
    const int d0   = dg << 1;         // 0,2,..,30
    const int lane = t & 63;
    const int wid  = t >> 6;          // wave id 0..15

    // Swizzle: 4 quad-siblings (same n-chunk) adjacent on the same XCD ->
    // shared 2 MB W chunk is L2-hit 3x.
    const int bid  = blockIdx.x;
    const int xcd  = bid & 7;
    const int j    = bid >> 3;                    // 0..63
    const int cg   = xcd * (CG / 8) + (j >> 2);   // 0..127
    const int quad = j & 3;                       // 0..3
    const int nbase = cg * NCHB;
    const int bbase = quad * BQ;

    __shared__ float4 xs[BQ][NCHB * DIN / 4];     // 8 KB: x[bquad][16 n][16 i]

    if (t < BQ * NCHB * DIN / 4) {                // 512 float4
        const int bb = t >> 6;
        const int k  = t & 63;
        xs[bb][k] = ((const float4*)x)[(size_t)(bbase + bb) * (NIN * DIN / 4)
                                       + (size_t)nbase * (DIN / 4) + k];
    }

    float acc0[BQ], acc1[BQ];                     // 16 VGPRs
#pragma unroll
    for (int bb = 0; bb < BQ; ++bb) { acc0[bb] = 0.f; acc1[bb] = 0.f; }

    __syncthreads();

    if constexpr (PASS == 1) {
        for (int nn = 0; nn < NCHB; ++nn) {
            const float4* wr = (const float4*)(W +
                (((size_t)(nbase + nn) * NOUT + o) * DOUT + d0) * DIN);
#pragma unroll
            for (int q = 0; q < 4; ++q) {         // W frag = 8 regs at a time
                const float4 w0 = wr[q];          // row d0,   i-chunk q
                const float4 w1 = wr[4 + q];      // row d0+1, i-chunk q
#pragma unroll
                for (int bb = 0; bb < BQ; ++bb) {
                    const float4 xv = xs[bb][nn * 4 + q];
                    acc0[bb] += w0.x*xv.x + w0.y*xv.y + w0.z*xv.z + w0.w*xv.w;
                    acc1[bb] += w1.x*xv.x + w1.y*xv.y + w1.z*xv.z + w1.w*xv.w;
                }
            }
        }
    } else {
        __shared__ float lg[BQ * NOUT];           // 2 KB logits
        __shared__ float cs[BQ * NOUT];           // 2 KB softmax weights
        for (int nn = 0; nn < NCHB; ++nn) {
            const float4* wr = (const float4*)(W +
                (((size_t)(nbase + nn) * NOUT + o) * DOUT + d0) * DIN);
            float u0r[BQ], u1r[BQ];               // 16 VGPRs, live across barriers
#pragma unroll
            for (int bb = 0; bb < BQ; ++bb) { u0r[bb] = 0.f; u1r[bb] = 0.f; }
#pragma unroll
            for (int q = 0; q < 4; ++q) {
                const float4 w0 = wr[q];
                const float4 w1 = wr[4 + q];
#pragma unroll
                for (int bb = 0; bb < BQ; ++bb) {
                    const float4 xv = xs[bb][nn * 4 + q];
                    u0r[bb] += w0.x*xv.x + w0.y*xv.y + w0.z*xv.z + w0.w*xv.w;
                    u1r[bb] += w1.x*xv.x + w1.y*xv.y + w1.z*xv.z + w1.w*xv.w;
                }
            }
            // logit partials -> lg[bb][o]
#pragma unroll
            for (int bb = 0; bb < BQ; ++bb) {
                const float2 vv = ((const float2*)v_in)[
                    (size_t)(bbase + bb) * (NOUT * DOUT / 2) + o * (DOUT / 2) + dg];
                float p = u0r[bb] * vv.x + u1r[bb] * vv.y;
                p += __shfl_xor(p, 1);
                p += __shfl_xor(p, 2);
                p += __shfl_xor(p, 4);
                p += __shfl_xor(p, 8);            // sum over 16-lane d-group
                if (dg == 0) lg[bb * NOUT + o] = p;
            }
            __syncthreads();
            // block-level softmax dedup: wave w handles batch bb=w (waves 0..7)
            if (wid < BQ) {
                const float e = __expf(lg[wid * NOUT + lane]);
                float sm = e;
#pragma unroll
                for (int m = 1; m < 64; m <<= 1) sm += __shfl_xor(sm, m);
                cs[wid * NOUT + lane] = e / sm;   // no max-sub: |logit| << 88
            }
            __syncthreads();
#pragma unroll
            for (int bb = 0; bb < BQ; ++bb) {
                const float c = cs[bb * NOUT + o];
                acc0[bb] += c * u0r[bb];
                acc1[bb] += c * u1r[bb];
            }
        }
    }

    const float scale = (PASS == 1) ? (1.0f / 64.0f) : 1.0f;
    if constexpr (ATOMIC) {
#pragma unroll
        for (int bb = 0; bb < BQ; ++bb) {
            float* dst = &s_out[((size_t)(bbase + bb) * NOUT + o) * DOUT + d0];
            atomicAdd(dst,     acc0[bb] * scale);
            atomicAdd(dst + 1, acc1[bb] * scale);
        }
    } else {
        // streaming coalesced partial store: part[(cg*4+quad)][bb][o][dg]
        float2* base = part + (size_t)(cg * 4 + quad) * PART_PER_BLK;
#pragma unroll
        for (int bb = 0; bb < BQ; ++bb)
            base[bb * (NOUT * DOUT / 2) + o * (DOUT / 2) + dg] =
                make_float2(acc0[bb] * scale, acc1[bb] * scale);
    }
}

// sum 128 chunk-partials per element, then squash per (b,o) row (16 lanes)
__global__ __launch_bounds__(256)
void reduce_squash(const float2* __restrict__ part, float* __restrict__ vout,
                   int accumulate)
{
    const int id = blockIdx.x * 256 + threadIdx.x;   // 0..32767
    const int dg = id & 15;
    const int o  = (id >> 4) & 63;
    const int b  = id >> 10;
    const int quad = b >> 3, bb = b & 7;
    const size_t base = (size_t)bb * (NOUT * DOUT / 2) + o * (DOUT / 2) + dg;

    float2 a0 = make_float2(0.f, 0.f), a1 = make_float2(0.f, 0.f);
    for (int cg = 0; cg < CG; cg += 2) {
        const float2 p0 = part[(size_t)(cg * 4 + quad) * PART_PER_BLK + base];
        const float2 p1 = part[(size_t)((cg + 1) * 4 + quad) * PART_PER_BLK + base];
        a0.x += p0.x; a0.y += p0.y;
        a1.x += p1.x; a1.y += p1.y;
    }
    const float sx = a0.x + a1.x, sy = a0.y + a1.y;

    float sq = sx * sx + sy * sy;
    sq += __shfl_xor(sq, 1);
    sq += __shfl_xor(sq, 2);
    sq += __shfl_xor(sq, 4);
    sq += __shfl_xor(sq, 8);        // row (b,o) = 16-lane group
    const float f = sq / ((1.0f + sq) * sqrtf(sq + 1e-8f));

    float2* vo = (float2*)vout;
    float2 r = make_float2(sx * f, sy * f);
    if (accumulate) {
        const float2 old = vo[id];
        r.x += old.x; r.y += old.y;
    }
    vo[id] = r;
}

// fallback squash for the atomic path
__global__ void squash_k(const float* __restrict__ s, float* __restrict__ vout,
                         int accumulate)
{
    const int idx = blockIdx.x * 256 + threadIdx.x;   // 65536 elements
    const float val = s[idx];
    float sq = val * val;
#pragma unroll
    for (int m = 1; m < 32; m <<= 1) sq += __shfl_xor(sq, m);
    const float f = sq / ((1.0f + sq) * sqrtf(sq + 1e-8f));
    const float v = val * f;
    if (accumulate) vout[idx] += v;
    else            vout[idx] = v;
}

extern "C" void kernel_launch(void* const* d_in, const int* in_sizes, int n_in,
                              void* d_out, int out_size, void* d_ws, size_t ws_size,
                              hipStream_t stream)
{
    (void)in_sizes; (void)n_in; (void)out_size;
    const float* x = (const float*)d_in[0];
    const float* W = (const float*)d_in[1];
    float* out = (float*)d_out;

    const size_t partBytes = (size_t)NBLK * PART_PER_BLK * sizeof(float2); // 32 MB
    const size_t vBytes    = (size_t)B_ * NOUT * DOUT * sizeof(float);     // 256 KB

    if (ws_size >= partBytes + vBytes) {
        // ---- partial-sum path (no global atomics)
        float2* part = (float2*)d_ws;
        float*  vA   = (float*)((char*)d_ws + partBytes);

        caps_pass<1, false><<<dim3(NBLK), dim3(TPB), 0, stream>>>(W, x, nullptr, nullptr, part);
        reduce_squash<<<dim3(128), dim3(256), 0, stream>>>(part, vA, 0);   // vA = v1

        caps_pass<2, false><<<dim3(NBLK), dim3(TPB), 0, stream>>>(W, x, vA, nullptr, part);
        reduce_squash<<<dim3(128), dim3(256), 0, stream>>>(part, vA, 1);   // vA = v1+v2

        caps_pass<2, false><<<dim3(NBLK), dim3(TPB), 0, stream>>>(W, x, vA, nullptr, part);
        reduce_squash<<<dim3(128), dim3(256), 0, stream>>>(part, out, 0);  // out = v3
    } else {
        // ---- atomic fallback
        float* s  = (float*)d_ws;
        float* vA = s + B_ * NOUT * DOUT;

        hipMemsetAsync(s, 0, vBytes, stream);
        caps_pass<1, true><<<dim3(NBLK), dim3(TPB), 0, stream>>>(W, x, nullptr, s, nullptr);
        squash_k<<<dim3(256), dim3(256), 0, stream>>>(s, vA, 0);

        hipMemsetAsync(s, 0, vBytes, stream);
        caps_pass<2, true><<<dim3(NBLK), dim3(TPB), 0, stream>>>(W, x, vA, s, nullptr);
        squash_k<<<dim3(256), dim3(256), 0, stream>>>(s, vA, 1);

        hipMemsetAsync(s, 0, vBytes, stream);
        caps_pass<2, true><<<dim3(NBLK), dim3(TPB), 0, stream>>>(W, x, vA, s, nullptr);
        squash_k<<<dim3(256), dim3(256), 0, stream>>>(s, out, 0);
    }
}

// Round 8
// 599.009 us; speedup vs baseline: 3.4049x; 3.4049x over previous
//
#include <hip/hip_runtime.h>

// RoutingCapsules on MI355X (gfx950)
// x: [B=32, Nin=2048, Din=16] f32
// W: [1, Nin=2048, Nout=64, Dout=32, Din=16] f32
// out v: [B=32, Nout=64, Dout=32] f32
//
// 3 fused W-sweeps (u_hat recomputed, never materialized):
//   pass1: c uniform     -> s1 = (1/64) sum_n u_hat        -> v1
//   pass2: logits=u.v1   -> s2                             -> v2
//   pass3: logits=u.(v1+v2)  (b3 = a1+a2)                  -> v3 = out
//
// Round-8: round 7 proved keeping u[16 regs] live across barriers re-spills
// (64-reg allocator ceiling; 1.79 GB scratch writes). Round 6 (u-stash in LDS,
// 56 VGPR, no spill) had the right register budget; its cost was the REDUNDANT
// per-thread softmax (8 exp + 8 div + 48 shfl per thread per nn -> 277 us).
// This round: round-6 register structure + round-7 block-level softmax dedup
// (waves 0-7 compute c[bb][o] once; everyone reads it). 2 barriers/nn,
// single-buffered lg/cs (race-checked).

#define B_   32
#define NIN  2048
#define DIN  16
#define NOUT 64
#define DOUT 32
#define BQ   8                          // batches per block
#define NCHB 16                         // n per block
#define CG   (NIN / NCHB)               // 128 chunk-groups
#define NBLK (CG * (B_ / BQ))           // 512 blocks
#define TPB  1024
#define PART_PER_BLK (BQ * NOUT * DOUT / 2)   // 8192 float2 per block (64 KB)

template<int PASS, bool ATOMIC>
__global__ __launch_bounds__(TPB)
void caps_pass(const float* __restrict__ W, const float* __restrict__ x,
               const float* __restrict__ v_in, float* __restrict__ s_out,
               float2* __restrict__ part)
{
    const int t    = threadIdx.x;     // 0..1023
    const int o    = t >> 4;          // 0..63   capsule-out index
    const int dg   = t & 15;          // 0..15
    const int d0   = dg << 1;         // 0,2,..,30
    const int lane = t & 63;
    const int wid  = t >> 6;          // wave id 0..15

    // Swizzle: 4 quad-siblings (same n-chunk) adjacent on the same XCD ->
    // shared 2 MB W chunk is L2-hit 3x.
    const int bid  = blockIdx.x;
    const int xcd  = bid & 7;
    const int j    = bid >> 3;                    // 0..63
    const int cg   = xcd * (CG / 8) + (j >> 2);   // 0..127
    const int quad = j & 3;                       // 0..3
    const int nbase = cg * NCHB;
    const int bbase = quad * BQ;

    __shared__ float4 xs[BQ][NCHB * DIN / 4];     // 8 KB: x[bquad][16 n][16 i]

    if (t < BQ * NCHB * DIN / 4) {                // 512 float4
        const int bb = t >> 6;
        const int k  = t & 63;
        xs[bb][k] = ((const float4*)x)[(size_t)(bbase + bb) * (NIN * DIN / 4)
                                       + (size_t)nbase * (DIN / 4) + k];
    }

    float acc0[BQ], acc1[BQ];                     // 16 VGPRs
#pragma unroll
    for (int bb = 0; bb < BQ; ++bb) { acc0[bb] = 0.f; acc1[bb] = 0.f; }

    __syncthreads();

    if constexpr (PASS == 1) {
        for (int nn = 0; nn < NCHB; ++nn) {
            const float4* wp = (const float4*)(W +
                (((size_t)(nbase + nn) * NOUT + o) * DOUT + d0) * DIN);
            float4 w[8];                          // 32 VGPRs (round-6 verified)
#pragma unroll
            for (int q = 0; q < 8; ++q) w[q] = wp[q];
#pragma unroll
            for (int bb = 0; bb < BQ; ++bb) {
                const float4* xr = &xs[bb][nn * 4];
                float u0 = 0.f, u1 = 0.f;
#pragma unroll
                for (int q = 0; q < 4; ++q) {
                    const float4 xv = xr[q];
                    u0 += w[q].x*xv.x + w[q].y*xv.y + w[q].z*xv.z + w[q].w*xv.w;
                    u1 += w[4+q].x*xv.x + w[4+q].y*xv.y + w[4+q].z*xv.z + w[4+q].w*xv.w;
                }
                acc0[bb] += u0;
                acc1[bb] += u1;
            }
        }
    } else {
        __shared__ float  lg[BQ * NOUT];          // 2 KB logits
        __shared__ float  cs[BQ * NOUT];          // 2 KB softmax weights
        __shared__ float2 ustash[BQ][TPB];        // 64 KB, thread-private slots
        for (int nn = 0; nn < NCHB; ++nn) {
            // ---- phase A: u into LDS stash + logit partials (round-6 structure)
            const float4* wp = (const float4*)(W +
                (((size_t)(nbase + nn) * NOUT + o) * DOUT + d0) * DIN);
            float4 w[8];
#pragma unroll
            for (int q = 0; q < 8; ++q) w[q] = wp[q];
#pragma unroll
            for (int bb = 0; bb < BQ; ++bb) {
                const float4* xr = &xs[bb][nn * 4];
                float u0 = 0.f, u1 = 0.f;
#pragma unroll
                for (int q = 0; q < 4; ++q) {
                    const float4 xv = xr[q];
                    u0 += w[q].x*xv.x + w[q].y*xv.y + w[q].z*xv.z + w[q].w*xv.w;
                    u1 += w[4+q].x*xv.x + w[4+q].y*xv.y + w[4+q].z*xv.z + w[4+q].w*xv.w;
                }
                const float2 vv = ((const float2*)v_in)[
                    (size_t)(bbase + bb) * (NOUT * DOUT / 2) + o * (DOUT / 2) + dg];
                float p = u0 * vv.x + u1 * vv.y;
                p += __shfl_xor(p, 1);
                p += __shfl_xor(p, 2);
                p += __shfl_xor(p, 4);
                p += __shfl_xor(p, 8);            // sum over 16-lane d-group
                if (dg == 0) lg[bb * NOUT + o] = p;
                ustash[bb][t] = make_float2(u0, u1);
            }
            __syncthreads();
            // ---- phase B: softmax dedup -- wave bb handles batch bb (waves 0..7)
            if (wid < BQ) {
                const float e = __expf(lg[wid * NOUT + lane]);
                float sm = e;
#pragma unroll
                for (int m = 1; m < 64; m <<= 1) sm += __shfl_xor(sm, m);
                cs[wid * NOUT + lane] = e / sm;   // no max-sub: |logit| << 88
            }
            __syncthreads();
            // ---- phase C: weighted accumulate from stash (broadcast cs reads)
#pragma unroll
            for (int bb = 0; bb < BQ; ++bb) {
                const float c = cs[bb * NOUT + o];
                const float2 u = ustash[bb][t];
                acc0[bb] += c * u.x;
                acc1[bb] += c * u.y;
            }
        }
    }

    const float scale = (PASS == 1) ? (1.0f / 64.0f) : 1.0f;
    if constexpr (ATOMIC) {
#pragma unroll
        for (int bb = 0; bb < BQ; ++bb) {
            float* dst = &s_out[((size_t)(bbase + bb) * NOUT + o) * DOUT + d0];
            atomicAdd(dst,     acc0[bb] * scale);
            atomicAdd(dst + 1, acc1[bb] * scale);
        }
    } else {
        // streaming coalesced partial store: part[(cg*4+quad)][bb][o][dg]
        float2* base = part + (size_t)(cg * 4 + quad) * PART_PER_BLK;
#pragma unroll
        for (int bb = 0; bb < BQ; ++bb)
            base[bb * (NOUT * DOUT / 2) + o * (DOUT / 2) + dg] =
                make_float2(acc0[bb] * scale, acc1[bb] * scale);
    }
}

// sum 128 chunk-partials per element, then squash per (b,o) row (16 lanes)
__global__ __launch_bounds__(256)
void reduce_squash(const float2* __restrict__ part, float* __restrict__ vout,
                   int accumulate)
{
    const int id = blockIdx.x * 256 + threadIdx.x;   // 0..32767
    const int dg = id & 15;
    const int o  = (id >> 4) & 63;
    const int b  = id >> 10;
    const int quad = b >> 3, bb = b & 7;
    const size_t base = (size_t)bb * (NOUT * DOUT / 2) + o * (DOUT / 2) + dg;

    float2 a0 = make_float2(0.f, 0.f), a1 = make_float2(0.f, 0.f);
    for (int cg = 0; cg < CG; cg += 2) {
        const float2 p0 = part[(size_t)(cg * 4 + quad) * PART_PER_BLK + base];
        const float2 p1 = part[(size_t)((cg + 1) * 4 + quad) * PART_PER_BLK + base];
        a0.x += p0.x; a0.y += p0.y;
        a1.x += p1.x; a1.y += p1.y;
    }
    const float sx = a0.x + a1.x, sy = a0.y + a1.y;

    float sq = sx * sx + sy * sy;
    sq += __shfl_xor(sq, 1);
    sq += __shfl_xor(sq, 2);
    sq += __shfl_xor(sq, 4);
    sq += __shfl_xor(sq, 8);        // row (b,o) = 16-lane group
    const float f = sq / ((1.0f + sq) * sqrtf(sq + 1e-8f));

    float2* vo = (float2*)vout;
    float2 r = make_float2(sx * f, sy * f);
    if (accumulate) {
        const float2 old = vo[id];
        r.x += old.x; r.y += old.y;
    }
    vo[id] = r;
}

// fallback squash for the atomic path
__global__ void squash_k(const float* __restrict__ s, float* __restrict__ vout,
                         int accumulate)
{
    const int idx = blockIdx.x * 256 + threadIdx.x;   // 65536 elements
    const float val = s[idx];
    float sq = val * val;
#pragma unroll
    for (int m = 1; m < 32; m <<= 1) sq += __shfl_xor(sq, m);
    const float f = sq / ((1.0f + sq) * sqrtf(sq + 1e-8f));
    const float v = val * f;
    if (accumulate) vout[idx] += v;
    else            vout[idx] = v;
}

extern "C" void kernel_launch(void* const* d_in, const int* in_sizes, int n_in,
                              void* d_out, int out_size, void* d_ws, size_t ws_size,
                              hipStream_t stream)
{
    (void)in_sizes; (void)n_in; (void)out_size;
    const float* x = (const float*)d_in[0];
    const float* W = (const float*)d_in[1];
    float* out = (float*)d_out;

    const size_t partBytes = (size_t)NBLK * PART_PER_BLK * sizeof(float2); // 32 MB
    const size_t vBytes    = (size_t)B_ * NOUT * DOUT * sizeof(float);     // 256 KB

    if (ws_size >= partBytes + vBytes) {
        // ---- partial-sum path (no global atomics)
        float2* part = (float2*)d_ws;
        float*  vA   = (float*)((char*)d_ws + partBytes);

        caps_pass<1, false><<<dim3(NBLK), dim3(TPB), 0, stream>>>(W, x, nullptr, nullptr, part);
        reduce_squash<<<dim3(128), dim3(256), 0, stream>>>(part, vA, 0);   // vA = v1

        caps_pass<2, false><<<dim3(NBLK), dim3(TPB), 0, stream>>>(W, x, vA, nullptr, part);
        reduce_squash<<<dim3(128), dim3(256), 0, stream>>>(part, vA, 1);   // vA = v1+v2

        caps_pass<2, false><<<dim3(NBLK), dim3(TPB), 0, stream>>>(W, x, vA, nullptr, part);
        reduce_squash<<<dim3(128), dim3(256), 0, stream>>>(part, out, 0);  // out = v3
    } else {
        // ---- atomic fallback
        float* s  = (float*)d_ws;
        float* vA = s + B_ * NOUT * DOUT;

        hipMemsetAsync(s, 0, vBytes, stream);
        caps_pass<1, true><<<dim3(NBLK), dim3(TPB), 0, stream>>>(W, x, nullptr, s, nullptr);
        squash_k<<<dim3(256), dim3(256), 0, stream>>>(s, vA, 0);

        hipMemsetAsync(s, 0, vBytes, stream);
        caps_pass<2, true><<<dim3(NBLK), dim3(TPB), 0, stream>>>(W, x, vA, s, nullptr);
        squash_k<<<dim3(256), dim3(256), 0, stream>>>(s, vA, 1);

        hipMemsetAsync(s, 0, vBytes, stream);
        caps_pass<2, true><<<dim3(NBLK), dim3(TPB), 0, stream>>>(W, x, vA, s, nullptr);
        squash_k<<<dim3(256), dim3(256), 0, stream>>>(s, out, 0);
    }
}